// Round 2
// baseline (153.215 us; speedup 1.0000x reference)
//
#include <hip/hip_runtime.h>
#include <hip/hip_bf16.h>

typedef unsigned short u16;
typedef unsigned int u32;
typedef __attribute__((ext_vector_type(8))) short bf16x8;
typedef __attribute__((ext_vector_type(4))) float floatx4;

__device__ __forceinline__ u16 f2bf(float f){
    union{float f;u32 i;}v; v.f=f; u32 r=v.i+0x7FFFu+((v.i>>16)&1u); return (u16)(r>>16);
}
__device__ __forceinline__ u32 pkbf(float a, float b){
    union { __hip_bfloat162 h; u32 u; } cv;
    cv.h = __float22bfloat162_rn(float2{a, b});
    return cv.u;
}

#define DD 512
#define NTOK 128

// ---------------------------------------------------------------------------
// prep_t: LDS-free transpose+convert (R1-verified).
//   blocks 0..127 : W1 rows 0..1023 (fp32 [1024][512]) -> W1T bf16 [512 c][1024 k]
//   blocks 128..159: W2 (fp32 [512][256])              -> W2T bf16 [256 c][512 k]
// ---------------------------------------------------------------------------
__global__ __launch_bounds__(512) void prep_t(
    const float* __restrict__ W1, const float* __restrict__ W2,
    u16* __restrict__ W1T, u16* __restrict__ W2T)
{
    const int bid = blockIdx.x;
    const float* src; u16* dst; int sstride, dstride, kt, ct;
    if (bid < 128) { kt = bid >> 3; ct = bid & 7;  src = W1; sstride = 512; dst = W1T; dstride = 1024; }
    else { int t = bid - 128; kt = t >> 2; ct = t & 3; src = W2; sstride = 256; dst = W2T; dstride = 512; }
    const int cl = threadIdx.x & 63;
    const int kchunk = (threadIdx.x >> 6) << 3;
    const int srow = kt * 64 + kchunk, scol = ct * 64 + cl;
    float v[8];
#pragma unroll
    for (int i = 0; i < 8; ++i) v[i] = src[(size_t)(srow + i) * sstride + scol];
    uint4 o = make_uint4(pkbf(v[0], v[1]), pkbf(v[2], v[3]),
                         pkbf(v[4], v[5]), pkbf(v[6], v[7]));
    *(uint4*)(dst + (size_t)scol * dstride + srow) = o;
}

// ---------------------------------------------------------------------------
// prep_g (R1-verified structure): Hf = features @ [W1a|W1b], K=512.
// Output now FP32 (removes bf16 unpack from fused_main's A-stage; HBM at
// <1% of peak makes the 2x bytes free and the per-b slab stays L2-resident).
// bN<8 -> Hf1b (+b1 folded), bN>=8 -> Hf2.
// ---------------------------------------------------------------------------
__global__ __launch_bounds__(512) void prep_g(
    const float* __restrict__ features, const u16* __restrict__ W1T,
    const float* __restrict__ b1, float* __restrict__ Hf1b, float* __restrict__ Hf2)
{
    const int bM = blockIdx.x, bN = blockIdx.y;
    const int tid = threadIdx.x;
    const int wid = tid >> 6, lane = tid & 63, lrow = lane & 15, quad = lane >> 4;
    const int wm = wid >> 1, wn = wid & 1;
    __shared__ __align__(16) u16 At[64 * 64];
    __shared__ __align__(16) u16 Btl[64 * 64];

    floatx4 acc[2];
    acc[0] = (floatx4)(0.0f); acc[1] = (floatx4)(0.0f);

    const int m = tid >> 3, seg = tid & 7, sw = m & 7;
    const int zoff = (bN >> 3) * 512;
    const u16* bsrc_lane = W1T
        + (size_t)((bN & 7) * 64 + wid * 8 + (lane >> 3)) * 1024
        + zoff + (((lane & 7) ^ (lane >> 3)) << 3);

    for (int kc = 0; kc < 8; ++kc) {
        const int k0 = kc * 64;
        __builtin_amdgcn_global_load_lds(
            (const __attribute__((address_space(1))) u32*)(bsrc_lane + k0),
            (__attribute__((address_space(3))) u32*)(Btl + wid * 512), 16, 0, 0);
        {   // stage A: 8 fp32 -> 8 bf16, one uint4, XOR-swizzled
            const float4* srcp = (const float4*)(features + (size_t)(bM * 64 + m) * DD + k0 + seg * 8);
            float4 f0 = srcp[0], f1 = srcp[1];
            *(uint4*)(At + m * 64 + ((seg ^ sw) << 3)) =
                make_uint4(pkbf(f0.x, f0.y), pkbf(f0.z, f0.w), pkbf(f1.x, f1.y), pkbf(f1.z, f1.w));
        }
        __syncthreads();
#pragma unroll
        for (int ks = 0; ks < 2; ++ks) {
            const int ch = ks * 4 + quad;
            int r = wm * 16 + lrow;
            bf16x8 afr = *(const bf16x8*)(At + r * 64 + ((ch ^ (r & 7)) << 3));
#pragma unroll
            for (int j = 0; j < 2; ++j) {
                int c = wn * 32 + j * 16 + lrow;
                bf16x8 bfr = *(const bf16x8*)(Btl + c * 64 + ((ch ^ (c & 7)) << 3));
                acc[j] = __builtin_amdgcn_mfma_f32_16x16x32_bf16(afr, bfr, acc[j], 0, 0, 0);
            }
        }
        __syncthreads();
    }
    float* outp = (bN >> 3) ? Hf2 : Hf1b;
#pragma unroll
    for (int j = 0; j < 2; ++j) {
        int col = (bN & 7) * 64 + wn * 32 + j * 16 + lrow;
        float bb = (bN >> 3) ? 0.0f : b1[col];
#pragma unroll
        for (int r = 0; r < 4; ++r) {
            int row = bM * 64 + wm * 16 + quad * 4 + r;
            outp[(size_t)row * DD + col] = acc[j][r] + bb;
        }
    }
}

// ---------------------------------------------------------------------------
// Fused main — exact R0 frame (proven 56.3 us, VGPR=64). Single diff this
// round: all A-stage operands are FP32 (Hf2 fp32 from prep_g; s1/c0/c1 fp32
// in LDS), eliminating the 8 bf16-unpack VALU ops per 2 elements that made
// VALUBusy ~2x the MFMA pipe. Epilogue and sync structure untouched.
// ---------------------------------------------------------------------------
__global__ __launch_bounds__(512) void fused_main(
    const float* __restrict__ Hf1b, const float* __restrict__ Hf2,
    const u16* __restrict__ W2T, const float* __restrict__ W1,
    const float* __restrict__ b2, const float* __restrict__ W3,
    const float* __restrict__ b3, const float* __restrict__ positions,
    float* __restrict__ out)
{
    const int b = blockIdx.x, n = blockIdx.y;     // b fastest -> XCD = b
    const int tid = threadIdx.x;
    const int base_bn = b * NTOK + n;
    const int wid = tid >> 6, lane = tid & 63, lrow = lane & 15, quad = lane >> 4;

    __shared__ __align__(16) float c0f[DD], c1f[DD], s1f[DD];  // fp32 coefs, 6 KB
    __shared__ __align__(16) u16 w3t[16 * 264];                // W3^T padded, 8.25 KB
    __shared__ __align__(16) char mbuf[49152];   // Atile 16K + Btile 32K | gh 34K
    u16* Atile = (u16*)mbuf;                     // [128][64] swizzled
    u16* Btile = (u16*)(mbuf + 16384);           // [256][64] swizzled
    u16* gh    = (u16*)mbuf;                     // [128][136] epilogue

    // ---- phase 0 ----
    {
        int k = tid;  // 512 threads == DD
        c0f[k] = W1[(size_t)1024 * DD + k];
        c1f[k] = W1[(size_t)1025 * DD + k];
        s1f[k] = Hf1b[(size_t)base_bn * DD + k];   // b1 already folded
    }
    {   // w3t: W3 (256x4 fp32) transposed, padded to 16 cols, bf16
        int c = tid & 15, kb2 = tid >> 4;          // kb2 0..31
        int k0w = kb2 * 8;
        u32 wv[4];
#pragma unroll
        for (int p = 0; p < 4; ++p) {
            int ka = k0w + p * 2;
            u16 va = (c < 4) ? f2bf(W3[ka * 4 + c])       : (u16)0;
            u16 vb = (c < 4) ? f2bf(W3[(ka + 1) * 4 + c]) : (u16)0;
            wv[p] = (u32)va | ((u32)vb << 16);
        }
        *(uint2*)(w3t + c * 264 + k0w)     = make_uint2(wv[0], wv[1]);
        *(uint2*)(w3t + c * 264 + k0w + 4) = make_uint2(wv[2], wv[3]);
    }
    const int mrow = tid >> 2, seg = tid & 3, swA = mrow & 7;
    float px, py;
    {
        float pnx = positions[(size_t)base_bn * 2 + 0];
        float pny = positions[(size_t)base_bn * 2 + 1];
        px = pnx - positions[(size_t)(b * NTOK + mrow) * 2 + 0];
        py = pny - positions[(size_t)(b * NTOK + mrow) * 2 + 1];
    }
    // B-DMA lane source pointer (q-invariant swizzle, R8-proven)
    const int csrc = lane >> 3, wsrc = lane & 7;
    const u16* bsrc_lane = W2T + csrc * DD + ((wsrc ^ csrc) << 3);
    __syncthreads();

    const int wm = wid >> 2, wn = wid & 3;       // main GEMM 2x4 wave grid
    floatx4 acc[4][4];
#pragma unroll
    for (int i = 0; i < 4; ++i)
#pragma unroll
        for (int j = 0; j < 4; ++j) acc[i][j] = (floatx4)(0.0f);

    const float* hf2p = Hf2 + (size_t)(b * NTOK + mrow) * DD;

    // ---- K loop ----
    for (int kc = 0; kc < 8; ++kc) {
        const int k0 = kc * 64;
        // stage B via LDS-DMA first (zero data regs; latency hidden by stage-A)
#pragma unroll
        for (int q = 0; q < 4; ++q) {
            const int slot = wid * 4 + q;        // wave-uniform
            __builtin_amdgcn_global_load_lds(
                (const __attribute__((address_space(1))) u32*)(bsrc_lane + slot * 8 * DD + k0),
                (__attribute__((address_space(3))) u32*)(Btile + slot * 512), 16, 0, 0);
        }

        const int kb = k0 + seg * 16;
        {   // stage A: h = relu(hf2 + s1 + px*c0 + py*c1), 16 elems, all fp32
            float hbuf[16], sbuf[16], abuf[16], bbuf[16];
#pragma unroll
            for (int t = 0; t < 4; ++t) {
                float4 hv = *(const float4*)(hf2p + kb + t * 4);
                float4 sv = *(const float4*)(s1f + kb + t * 4);
                float4 av = *(const float4*)(c0f + kb + t * 4);
                float4 bv = *(const float4*)(c1f + kb + t * 4);
                hbuf[t*4+0] = hv.x; hbuf[t*4+1] = hv.y; hbuf[t*4+2] = hv.z; hbuf[t*4+3] = hv.w;
                sbuf[t*4+0] = sv.x; sbuf[t*4+1] = sv.y; sbuf[t*4+2] = sv.z; sbuf[t*4+3] = sv.w;
                abuf[t*4+0] = av.x; abuf[t*4+1] = av.y; abuf[t*4+2] = av.z; abuf[t*4+3] = av.w;
                bbuf[t*4+0] = bv.x; bbuf[t*4+1] = bv.y; bbuf[t*4+2] = bv.z; bbuf[t*4+3] = bv.w;
            }
            u32 o[8];
#pragma unroll
            for (int i = 0; i < 8; ++i) {
                float v0 = fmaxf(fmaf(py, bbuf[2*i],   fmaf(px, abuf[2*i],   hbuf[2*i]   + sbuf[2*i])),   0.0f);
                float v1 = fmaxf(fmaf(py, bbuf[2*i+1], fmaf(px, abuf[2*i+1], hbuf[2*i+1] + sbuf[2*i+1])), 0.0f);
                o[i] = pkbf(v0, v1);
            }
            *(uint4*)(Atile + mrow * 64 + (((seg * 2    ) ^ swA) << 3)) = make_uint4(o[0], o[1], o[2], o[3]);
            *(uint4*)(Atile + mrow * 64 + (((seg * 2 + 1) ^ swA) << 3)) = make_uint4(o[4], o[5], o[6], o[7]);
        }
        __syncthreads();   // vmcnt(0)+lgkmcnt(0) drain: Atile and B-DMA ready
#pragma unroll
        for (int ks = 0; ks < 2; ++ks) {
            const int ch = ks * 4 + quad;
            bf16x8 afr[4], bfr[4];
#pragma unroll
            for (int i = 0; i < 4; ++i) {
                int r = wm * 64 + i * 16 + lrow;
                afr[i] = *(const bf16x8*)(Atile + r * 64 + ((ch ^ (r & 7)) << 3));
            }
#pragma unroll
            for (int j = 0; j < 4; ++j) {
                int c = wn * 64 + j * 16 + lrow;
                bfr[j] = *(const bf16x8*)(Btile + c * 64 + ((ch ^ (c & 7)) << 3));
            }
#pragma unroll
            for (int i = 0; i < 4; ++i)
#pragma unroll
                for (int j = 0; j < 4; ++j)
                    acc[i][j] = __builtin_amdgcn_mfma_f32_16x16x32_bf16(afr[i], bfr[j], acc[i][j], 0, 0, 0);
        }
        __syncthreads();
    }

    // ---- epilogue: relu(acc+b2) -> gh bf16 halves -> layer-3 MFMA (exact R0) ----
    float b2v[4];
#pragma unroll
    for (int j = 0; j < 4; ++j) b2v[j] = b2[wn * 64 + j * 16 + lrow];

    const int smrow = wid * 16;                  // per-wave epilogue row block
    floatx4 acc3 = (floatx4)(0.0f);
#pragma unroll
    for (int half = 0; half < 2; ++half) {
        __syncthreads();
        if ((wn >> 1) == half) {
#pragma unroll
            for (int i = 0; i < 4; ++i)
#pragma unroll
                for (int j = 0; j < 4; ++j)
#pragma unroll
                    for (int r = 0; r < 4; ++r) {
                        int row = wm * 64 + i * 16 + quad * 4 + r;
                        int col = (wn & 1) * 64 + j * 16 + lrow;
                        gh[row * 136 + col] = f2bf(fmaxf(acc[i][j][r] + b2v[j], 0.0f));
                    }
        }
        __syncthreads();
#pragma unroll
        for (int ks = 0; ks < 4; ++ks) {
            bf16x8 gfrag = *(const bf16x8*)(gh + (smrow + lrow) * 136 + ks * 32 + quad * 8);
            bf16x8 wfrag = *(const bf16x8*)(w3t + lrow * 264 + half * 128 + ks * 32 + quad * 8);
            acc3 = __builtin_amdgcn_mfma_f32_16x16x32_bf16(gfrag, wfrag, acc3, 0, 0, 0);
        }
    }
    if (lrow < 4) {
        float bo = b3[lrow];
#pragma unroll
        for (int r = 0; r < 4; ++r) {
            int row = smrow + quad * 4 + r;
            out[(size_t)base_bn * 512 + row * 4 + lrow] = acc3[r] + bo;
        }
    }
}

// ---------------------------------------------------------------------------
extern "C" void kernel_launch(void* const* d_in, const int* in_sizes, int n_in,
                              void* d_out, int out_size, void* d_ws, size_t ws_size,
                              hipStream_t stream)
{
    const float* features  = (const float*)d_in[0];
    const float* positions = (const float*)d_in[1];
    const float* W1 = (const float*)d_in[2];
    const float* b1 = (const float*)d_in[3];
    const float* W2 = (const float*)d_in[4];
    const float* b2 = (const float*)d_in[5];
    const float* W3 = (const float*)d_in[6];
    const float* b3 = (const float*)d_in[7];
    float* out = (float*)d_out;

    char* ws = (char*)d_ws;
    u16*   W2T  = (u16*)(ws);                  // 256*512*2  = 262144 B
    u16*   W1T  = (u16*)(ws + 262144);         // 512*1024*2 = 1048576 B
    float* Hf1b = (float*)(ws + 1310720);      // 1024*512*4 = 2097152 B
    float* Hf2  = (float*)(ws + 3407872);      // 1024*512*4 = 2097152 B (total 5.25 MB)

    prep_t<<<dim3(160), 512, 0, stream>>>(W1, W2, W1T, W2T);
    prep_g<<<dim3(16, 16), 512, 0, stream>>>(features, W1T, b1, Hf1b, Hf2);
    fused_main<<<dim3(8, 128), 512, 0, stream>>>(Hf1b, Hf2, W2T, W1, b2, W3, b3,
                                                 positions, out);
}